// Round 12
// baseline (45.012 us; speedup 1.0000x reference)
//
#include <hip/hip_runtime.h>
#include <hip/hip_bf16.h>
#include <math.h>

#define SEQ_LEN 32768
#define HID 1024
#define NBLK_E 2048          // energy blocks: 16 rows each
#define SWZ 997              // odd -> (bid*SWZ)&2047 is a bijection on [0,2048)

typedef float f32x4 __attribute__((ext_vector_type(4)));

// ---------------------------------------------------------------------------
// MEASUREMENT ROUND: kernels identical to R11; 8 empty dispatches appended.
// Delta vs R11's 32.8 us = 8 x per-node overhead. Determines whether the
// ~11 us unaccounted time is per-node (-> fuse to 1 node) or per-replay
// fixed (-> we are at the floor).
// ---------------------------------------------------------------------------
__global__ void k_noop() {}

// ---------------------------------------------------------------------------
// K1: v = W^T h, fetch-exact (R10).
// ---------------------------------------------------------------------------
__global__ void __launch_bounds__(1024) k_matvec(const float* __restrict__ W,
                                                 const float* __restrict__ hvec,
                                                 float* __restrict__ v) {
    const int t = threadIdx.x;
    const int ct = t & 31;
    const int dt = t >> 5;               // 0..31
    const int col = (blockIdx.x << 5) + ct;
    const int d0 = dt << 5;

    float acc = 0.f;
#pragma unroll 8
    for (int i = 0; i < 32; ++i) {
        const int d = d0 + i;
        acc = fmaf(hvec[d], W[(size_t)d * HID + col], acc);
    }

    __shared__ float red[32][33];
    red[dt][ct] = acc;
    __syncthreads();
    if (t < 32) {
        float s = 0.f;
#pragma unroll
        for (int i = 0; i < 32; ++i) s += red[i][t];
        v[(blockIdx.x << 5) + t] = s;
    }
}

// ---------------------------------------------------------------------------
// K2: energies[s] = enc[s,:] . v  (identical to R11)
// ---------------------------------------------------------------------------
__global__ void __launch_bounds__(256) k_energy(const float* __restrict__ enc,
                                                const float* __restrict__ v,
                                                float* __restrict__ energies,
                                                float2* __restrict__ bstats) {
    const int t = threadIdx.x;
    const int wave = t >> 6;
    const int lane = t & 63;
    const int chunk = (blockIdx.x * SWZ) & (NBLK_E - 1);
    const int row0 = (chunk << 4) + (wave << 2);

    const f32x4 vr0 = *reinterpret_cast<const f32x4*>(v +       (lane << 2));
    const f32x4 vr1 = *reinterpret_cast<const f32x4*>(v + 256 + (lane << 2));
    const f32x4 vr2 = *reinterpret_cast<const f32x4*>(v + 512 + (lane << 2));
    const f32x4 vr3 = *reinterpret_cast<const f32x4*>(v + 768 + (lane << 2));

    float m = -__builtin_inff();
    float z = 0.f;

    const f32x4* p = reinterpret_cast<const f32x4*>(enc + (size_t)row0 * HID) + lane;
    f32x4 a = p[0], b = p[64], c = p[128], d = p[192];

#pragma unroll
    for (int r = 0; r < 4; ++r) {
        f32x4 na, nb, nc, nd;
        if (r < 3) {
            const f32x4* q = p + (size_t)(r + 1) * 256;
            na = q[0]; nb = q[64]; nc = q[128]; nd = q[192];
        }
        const f32x4 s4 = a * vr0 + b * vr1 + c * vr2 + d * vr3;
        float acc = (s4.x + s4.y) + (s4.z + s4.w);
#pragma unroll
        for (int off = 32; off; off >>= 1) acc += __shfl_xor(acc, off, 64);
        if (lane == 0) energies[row0 + r] = acc;
        const float nm = fmaxf(m, acc);
        z = z * __expf(m - nm) + __expf(acc - nm);
        m = nm;
        a = na; b = nb; c = nc; d = nd;
    }

    __shared__ float wm[4], wz[4];
    if (lane == 0) { wm[wave] = m; wz[wave] = z; }
    __syncthreads();
    if (t == 0) {
        float M = fmaxf(fmaxf(wm[0], wm[1]), fmaxf(wm[2], wm[3]));
        float Z = wz[0] * __expf(wm[0] - M) + wz[1] * __expf(wm[1] - M)
                + wz[2] * __expf(wm[2] - M) + wz[3] * __expf(wm[3] - M);
        bstats[chunk] = make_float2(M, Z);
    }
}

// ---------------------------------------------------------------------------
// K3: global (M,Z) + write outputs (identical to R11)
// ---------------------------------------------------------------------------
__global__ void __launch_bounds__(256) k_final(const float* __restrict__ energies,
                                               const float2* __restrict__ bstats,
                                               float* __restrict__ out) {
    __shared__ float sm[256], sz[256];
    const int t = threadIdx.x;
    float m = -__builtin_inff();
    float z = 0.f;
#pragma unroll
    for (int i = 0; i < 8; ++i) {
        const float2 s = bstats[t + (i << 8)];
        const float nm = fmaxf(m, s.x);
        z = z * __expf(m - nm) + s.y * __expf(s.x - nm);
        m = nm;
    }
    sm[t] = m; sz[t] = z;
    __syncthreads();
    for (int off = 128; off; off >>= 1) {
        if (t < off) {
            const float m1 = sm[t], z1 = sz[t];
            const float m2 = sm[t + off], z2 = sz[t + off];
            const float M = fmaxf(m1, m2);
            sm[t] = M;
            sz[t] = z1 * __expf(m1 - M) + z2 * __expf(m2 - M);
        }
        __syncthreads();
    }
    const float M = sm[0];
    const float rZ = 1.f / sz[0];

    const size_t i = ((size_t)blockIdx.x << 9) + ((size_t)t << 1);
    const float2 e = *reinterpret_cast<const float2*>(energies + i);
    float2 o;
    o.x = __expf(e.x - M) * rZ;
    o.y = __expf(e.y - M) * rZ;
    *reinterpret_cast<float2*>(out + i) = o;
}

extern "C" void kernel_launch(void* const* d_in, const int* in_sizes, int n_in,
                              void* d_out, int out_size, void* d_ws, size_t ws_size,
                              hipStream_t stream) {
    const float* hidden = (const float*)d_in[0];   // [1,1,1024]
    const float* enc    = (const float*)d_in[1];   // [32768,1024]
    const float* W      = (const float*)d_in[2];   // [1024,1024]
    // d_in[3] (bias) cancels in softmax (constant shift) — never read.

    float* ws       = (float*)d_ws;
    float* v        = ws;                            // 1024 floats
    float* energies = ws + HID;                      // 32768 floats
    float2* bstats  = (float2*)(ws + HID + SEQ_LEN); // 2048 float2

    k_matvec<<<HID / 32, 1024, 0, stream>>>(W, hidden, v);
    k_energy<<<NBLK_E, 256, 0, stream>>>(enc, v, energies, bstats);
    k_final<<<SEQ_LEN / 512, 256, 0, stream>>>(energies, bstats, (float*)d_out);

    // 8 empty dispatches: measure per-node overhead (delta/8 vs R11).
    for (int i = 0; i < 8; ++i) k_noop<<<1, 64, 0, stream>>>();
}

// Round 13
// 40.837 us; speedup vs baseline: 1.1022x; 1.1022x over previous
//
#include <hip/hip_runtime.h>
#include <math.h>

#define SEQ_LEN 32768
#define HID 1024
#define NBLK 2048            // 16 rows per block
#define SWZ 997              // odd -> (bid*SWZ)&2047 bijective
#define RLX __ATOMIC_RELAXED
#define AGT __HIP_MEMORY_SCOPE_AGENT

typedef float f32x4 __attribute__((ext_vector_type(4)));

// Control state in a device global (harness never poisons module globals).
// Zero at load; last departing block re-zeroes -> deterministic replays.
// Word offsets (each counter/flag on its own 128B line):
#define VDONE      0
#define VFLAG(i)   (32 + ((i) << 5))     // 64 replicated v-ready flags
#define SUB(g)     (2080 + ((g) << 5))   // 64 group arrival counters
#define MASTER     4128
#define FLAGR(i)   (4160 + ((i) << 5))   // 8 replicated final flags
#define DEPART     4416
__device__ unsigned g_ctl[4448];

__device__ __forceinline__ unsigned ld32(const unsigned* p) { return __hip_atomic_load(p, RLX, AGT); }
__device__ __forceinline__ void st32(unsigned* p, unsigned v) { __hip_atomic_store(p, v, RLX, AGT); }
__device__ __forceinline__ unsigned long long ld64(const unsigned long long* p) { return __hip_atomic_load(p, RLX, AGT); }
__device__ __forceinline__ void st64(unsigned long long* p, unsigned long long v) { __hip_atomic_store(p, v, RLX, AGT); }
__device__ __forceinline__ unsigned add32(unsigned* p, unsigned v) { return __hip_atomic_fetch_add(p, v, RLX, AGT); }
__device__ __forceinline__ void vfence() { asm volatile("s_waitcnt vmcnt(0)" ::: "memory"); }
__device__ __forceinline__ void spin(unsigned* f) {
    for (int i = 0; i < (1 << 24); ++i) {          // bounded: fail -> wrong answer, not hang
        if (ld32(f)) return;
        __builtin_amdgcn_s_sleep(4);
    }
}
__device__ __forceinline__ void mzmerge(float& m, float& z, float m2, float z2) {
    const float M = fmaxf(m, m2);
    z = z * __expf(m - M) + z2 * __expf(m2 - M);
    m = M;
}

__global__ void __launch_bounds__(256)
k_all(const float* __restrict__ W, const float* __restrict__ hvec,
      const float* __restrict__ enc, unsigned* __restrict__ vglob,
      unsigned long long* __restrict__ bstats,
      unsigned long long* __restrict__ fstat,   // fstat[0]=(M,Z); energies at ((unsigned*)fstat)+2
      float* __restrict__ out) {
    const int t = threadIdx.x, bid = blockIdx.x;
    const int wave = t >> 6, lane = t & 63;
    unsigned* eglob = (unsigned*)fstat + 2;        // 32768 sc1-published energies

    __shared__ float v_lds[HID];
    __shared__ float wm[4], wz[4];
    __shared__ float sm[256], sz[256];
    __shared__ int s_role;
    __shared__ float2 s_mz;

    // ---- Phase 1 (blocks 0..31): v = W^T h, fetch-exact -------------------
    if (bid < 32) {
        const int ct = t & 31, dt = t >> 5;
        const int col = (bid << 5) + ct;
        float acc = 0.f;
        const int d0 = dt << 7;
#pragma unroll 8
        for (int i = 0; i < 128; ++i) {
            const int d = d0 + i;
            acc = fmaf(hvec[d], W[(size_t)d * HID + col], acc);
        }
        __shared__ float red[8][33];
        red[dt][ct] = acc;
        __syncthreads();
        if (t < 32) {
            float s = 0.f;
#pragma unroll
            for (int i = 0; i < 8; ++i) s += red[i][t];
            st32(vglob + (bid << 5) + t, __float_as_uint(s));   // sc1 -> MALL
        }
        __syncthreads();
        if (t == 0) {
            vfence();
            if (add32(g_ctl + VDONE, 1u) == 31u) {
#pragma unroll
                for (int i = 0; i < 64; ++i) st32(g_ctl + VFLAG(i), 1u);
            }
        }
    }

    // ---- all blocks: wait v-ready (<=32 pollers per replica line) ---------
    if (t == 0) spin(g_ctl + VFLAG(bid & 63));
    __syncthreads();

    // ---- v -> LDS via sc1 loads (XCD L2s may hold stale poison) -----------
#pragma unroll
    for (int i = 0; i < 4; ++i) {
        const int idx = (i << 8) + t;
        v_lds[idx] = __uint_as_float(ld32(vglob + idx));
    }
    __syncthreads();

    // ---- Phase 2: energies for 16 rows of chunk ---------------------------
    const int chunk = (bid * SWZ) & (NBLK - 1);
    {
        const int row0 = (chunk << 4) + (wave << 2);
        const f32x4 vr0 = *reinterpret_cast<const f32x4*>(v_lds +       (lane << 2));
        const f32x4 vr1 = *reinterpret_cast<const f32x4*>(v_lds + 256 + (lane << 2));
        const f32x4 vr2 = *reinterpret_cast<const f32x4*>(v_lds + 512 + (lane << 2));
        const f32x4 vr3 = *reinterpret_cast<const f32x4*>(v_lds + 768 + (lane << 2));

        float m = -__builtin_inff();
        float z = 0.f;

        const f32x4* p = reinterpret_cast<const f32x4*>(enc + (size_t)row0 * HID) + lane;
        f32x4 a = p[0], b = p[64], c = p[128], d = p[192];

#pragma unroll
        for (int r = 0; r < 4; ++r) {
            f32x4 na, nb, nc, nd;
            if (r < 3) {
                const f32x4* q = p + (size_t)(r + 1) * 256;
                na = q[0]; nb = q[64]; nc = q[128]; nd = q[192];
            }
            const f32x4 s4 = a * vr0 + b * vr1 + c * vr2 + d * vr3;
            float acc = (s4.x + s4.y) + (s4.z + s4.w);
#pragma unroll
            for (int off = 32; off; off >>= 1) acc += __shfl_xor(acc, off, 64);
            if (lane == 0) st32(eglob + row0 + r, __float_as_uint(acc));  // publish energy
            const float nm = fmaxf(m, acc);
            z = z * __expf(m - nm) + __expf(acc - nm);
            m = nm;
            a = na; b = nb; c = nc; d = nd;
        }
        if (lane == 0) { wm[wave] = m; wz[wave] = z; }
    }
    __syncthreads();

    // ---- arrive; last per 32-group -> leader (64 total) -------------------
    if (t == 0) {
        float M = wm[0], Z = wz[0];
        mzmerge(M, Z, wm[1], wz[1]);
        mzmerge(M, Z, wm[2], wz[2]);
        mzmerge(M, Z, wm[3], wz[3]);
        st64(bstats + chunk, __builtin_bit_cast(unsigned long long, make_float2(M, Z)));
        vfence();                                   // energies + bstat at MALL first
        int role = -1;
        if (add32(g_ctl + SUB(bid >> 5), 1u) == 31u)
            role = (int)add32(g_ctl + MASTER, 1u);  // 0..63
        s_role = role;
    }
    __syncthreads();
    const int role = s_role;
    if (role < 0) return;                           // 1984 blocks done

    // ---- tail: 64 leader blocks ------------------------------------------
    if (role == 63) {
        float m = -__builtin_inff(), z = 0.f;
#pragma unroll
        for (int i = 0; i < 8; ++i) {
            const float2 s = __builtin_bit_cast(float2, ld64(bstats + t + (i << 8)));
            mzmerge(m, z, s.x, s.y);
        }
        sm[t] = m; sz[t] = z;
        __syncthreads();
        for (int off = 128; off; off >>= 1) {
            if (t < off) {
                float m1 = sm[t], z1 = sz[t];
                mzmerge(m1, z1, sm[t + off], sz[t + off]);
                sm[t] = m1; sz[t] = z1;
            }
            __syncthreads();
        }
        if (t == 0) {
            st64(fstat, __builtin_bit_cast(unsigned long long, make_float2(sm[0], sz[0])));
            vfence();
#pragma unroll
            for (int i = 0; i < 8; ++i) st32(g_ctl + FLAGR(i), 1u);
        }
    } else {
        if (t == 0) spin(g_ctl + FLAGR(role & 7));  // <=8 pollers per line
    }
    __syncthreads();
    if (t == 0) s_mz = __builtin_bit_cast(float2, ld64(fstat));
    __syncthreads();

    // ---- write 512 outputs per tail block ---------------------------------
    const float M = s_mz.x;
    const float rZ = 1.f / s_mz.y;
    const int base = role << 9;
    const unsigned long long ebits =
        ld64(reinterpret_cast<const unsigned long long*>(eglob) + (base >> 1) + t);
    const float2 e = __builtin_bit_cast(float2, ebits);
    float2 o;
    o.x = __expf(e.x - M) * rZ;
    o.y = __expf(e.y - M) * rZ;
    *reinterpret_cast<float2*>(out + base + (t << 1)) = o;

    // ---- self-reset by last departing tail block --------------------------
    if (t == 0) {
        if (add32(g_ctl + DEPART, 1u) == 63u) {
            st32(g_ctl + VDONE, 0u);
#pragma unroll
            for (int i = 0; i < 64; ++i) { st32(g_ctl + VFLAG(i), 0u); st32(g_ctl + SUB(i), 0u); }
            st32(g_ctl + MASTER, 0u);
#pragma unroll
            for (int i = 0; i < 8; ++i) st32(g_ctl + FLAGR(i), 0u);
            st32(g_ctl + DEPART, 0u);
        }
    }
}

extern "C" void kernel_launch(void* const* d_in, const int* in_sizes, int n_in,
                              void* d_out, int out_size, void* d_ws, size_t ws_size,
                              hipStream_t stream) {
    const float* hidden = (const float*)d_in[0];   // [1,1,1024]
    const float* enc    = (const float*)d_in[1];   // [32768,1024]
    const float* W      = (const float*)d_in[2];   // [1024,1024]
    // d_in[3] (bias) cancels in softmax (constant shift) — never read.

    float* ws = (float*)d_ws;
    unsigned* vglob = (unsigned*)ws;                              // 1024 u32
    unsigned long long* bstats = (unsigned long long*)(ws + HID); // 2048 u64
    unsigned long long* fstat = bstats + 2048;                    // (M,Z) + 32768 energies

    k_all<<<NBLK, 256, 0, stream>>>(W, hidden, enc, vglob, bstats, fstat,
                                    (float*)d_out);
}